// Round 1
// baseline (5328.072 us; speedup 1.0000x reference)
//
#include <hip/hip_runtime.h>
#include <math.h>

#define BB 64
#define SS 200
#define TT 25
#define VV 32000
#define EE 256
#define HH 256
#define HID 512

// ---------------------------------------------------------------------------
// prep: pack w_hh (768x256) -> wT[k4][768][4] so scan reads float4 along K
// ---------------------------------------------------------------------------
__global__ void k_whh_pack(const float* __restrict__ wf, const float* __restrict__ wb,
                           float* __restrict__ oTf, float* __restrict__ oTb) {
    int gid = blockIdx.x * 256 + threadIdx.x;
    if (gid >= 2 * 768 * 256) return;
    const float* w = (gid < 768 * 256) ? wf : wb;
    float* o = (gid < 768 * 256) ? oTf : oTb;
    int g = gid % (768 * 256);
    int j = g >> 8;        // 0..767 output row of w_hh
    int kk = g & 255;      // 0..255
    o[(kk >> 2) * 3072 + j * 4 + (kk & 3)] = w[g];
}

// ---------------------------------------------------------------------------
// gi GEMM: C[12800][768] = gather(emb by src_flat) @ W^T + bias
// ---------------------------------------------------------------------------
__global__ __launch_bounds__(256) void k_gemm_gi(const int* __restrict__ src,
                                                 const float* __restrict__ emb,
                                                 const float* __restrict__ W,
                                                 const float* __restrict__ bias,
                                                 float* __restrict__ C) {
    __shared__ float As[32][68];
    __shared__ float Ws[32][68];
    __shared__ int toks[64];
    int tid = threadIdx.x, bx = blockIdx.x, by = blockIdx.y;
    if (tid < 64) toks[tid] = src[by * 64 + tid];
    __syncthreads();
    int tx = tid & 15, ty = tid >> 4;
    float acc[4][4] = {};
    for (int k0 = 0; k0 < 256; k0 += 32) {
#pragma unroll
        for (int l = 0; l < 2; ++l) {
            int f = tid + l * 256;
            int r = f >> 3, c4 = f & 7;
            float4 v = *(const float4*)(emb + (size_t)toks[r] * EE + k0 + c4 * 4);
            As[c4 * 4 + 0][r] = v.x; As[c4 * 4 + 1][r] = v.y;
            As[c4 * 4 + 2][r] = v.z; As[c4 * 4 + 3][r] = v.w;
            float4 w = *(const float4*)(W + (size_t)(bx * 64 + r) * 256 + k0 + c4 * 4);
            Ws[c4 * 4 + 0][r] = w.x; Ws[c4 * 4 + 1][r] = w.y;
            Ws[c4 * 4 + 2][r] = w.z; Ws[c4 * 4 + 3][r] = w.w;
        }
        __syncthreads();
#pragma unroll
        for (int kk = 0; kk < 32; ++kk) {
            float4 a = *(const float4*)&As[kk][ty * 4];
            float4 w = *(const float4*)&Ws[kk][tx * 4];
            acc[0][0] += a.x * w.x; acc[0][1] += a.x * w.y; acc[0][2] += a.x * w.z; acc[0][3] += a.x * w.w;
            acc[1][0] += a.y * w.x; acc[1][1] += a.y * w.y; acc[1][2] += a.y * w.z; acc[1][3] += a.y * w.w;
            acc[2][0] += a.z * w.x; acc[2][1] += a.z * w.y; acc[2][2] += a.z * w.z; acc[2][3] += a.z * w.w;
            acc[3][0] += a.w * w.x; acc[3][1] += a.w * w.y; acc[3][2] += a.w * w.z; acc[3][3] += a.w * w.w;
        }
        __syncthreads();
    }
#pragma unroll
    for (int i = 0; i < 4; ++i)
#pragma unroll
        for (int j = 0; j < 4; ++j) {
            int m = by * 64 + ty * 4 + i, n = bx * 64 + tx * 4 + j;
            C[(size_t)m * 768 + n] = acc[i][j] + bias[n];
        }
}

// ---------------------------------------------------------------------------
// recurrent scan: 64 blocks, block = (dir, 2 chains). h kept in LDS (fp32).
// ---------------------------------------------------------------------------
__global__ __launch_bounds__(256) void k_scan(const float* __restrict__ giF,
                                              const float* __restrict__ giB,
                                              const float* __restrict__ wTf,
                                              const float* __restrict__ wTb,
                                              const float* __restrict__ bhhf,
                                              const float* __restrict__ bhhb,
                                              float* __restrict__ states) {
    __shared__ float h0s[256];
    __shared__ float h1s[256];
    int bid = blockIdx.x, t = threadIdx.x;
    int dir = bid >> 5, jp = bid & 31;
    int j0 = jp * 2, j1 = jp * 2 + 1;
    const float* gi = dir ? giB : giF;
    const float* wT = dir ? wTb : wTf;
    const float* bhh = dir ? bhhb : bhhf;
    float br = bhh[t], bz = bhh[256 + t], bn = bhh[512 + t];
    h0s[t] = 0.f; h1s[t] = 0.f;
    __syncthreads();
    for (int s = 0; s < SS; ++s) {
        int srow = dir ? (SS - 1 - s) : s;
        const float* g0 = gi + ((size_t)srow * 64 + j0) * 768;
        const float* g1 = gi + ((size_t)srow * 64 + j1) * 768;
        float gir0 = g0[t], giz0 = g0[256 + t], gin0 = g0[512 + t];
        float gir1 = g1[t], giz1 = g1[256 + t], gin1 = g1[512 + t];
        float ar0 = 0, az0 = 0, an0 = 0, ar1 = 0, az1 = 0, an1 = 0;
#pragma unroll 4
        for (int k4 = 0; k4 < 64; ++k4) {
            float4 wr = *(const float4*)(wT + ((size_t)k4 * 768 + t) * 4);
            float4 wz = *(const float4*)(wT + ((size_t)k4 * 768 + 256 + t) * 4);
            float4 wn = *(const float4*)(wT + ((size_t)k4 * 768 + 512 + t) * 4);
            float4 h0 = *(const float4*)&h0s[k4 * 4];
            float4 h1 = *(const float4*)&h1s[k4 * 4];
            ar0 += h0.x * wr.x + h0.y * wr.y + h0.z * wr.z + h0.w * wr.w;
            az0 += h0.x * wz.x + h0.y * wz.y + h0.z * wz.z + h0.w * wz.w;
            an0 += h0.x * wn.x + h0.y * wn.y + h0.z * wn.z + h0.w * wn.w;
            ar1 += h1.x * wr.x + h1.y * wr.y + h1.z * wr.z + h1.w * wr.w;
            az1 += h1.x * wz.x + h1.y * wz.y + h1.z * wz.z + h1.w * wz.w;
            an1 += h1.x * wn.x + h1.y * wn.y + h1.z * wn.z + h1.w * wn.w;
        }
        float hold0 = h0s[t], hold1 = h1s[t];
        float r0 = 1.f / (1.f + expf(-(gir0 + ar0 + br)));
        float z0 = 1.f / (1.f + expf(-(giz0 + az0 + bz)));
        float n0 = tanhf(gin0 + r0 * (an0 + bn));
        float hn0 = (1.f - z0) * n0 + z0 * hold0;
        float r1 = 1.f / (1.f + expf(-(gir1 + ar1 + br)));
        float z1 = 1.f / (1.f + expf(-(giz1 + az1 + bz)));
        float n1 = tanhf(gin1 + r1 * (an1 + bn));
        float hn1 = (1.f - z1) * n1 + z1 * hold1;
        __syncthreads();
        h0s[t] = hn0; h1s[t] = hn1;
        __syncthreads();
        int off = dir ? 256 : 0;
        states[((size_t)srow * 64 + j0) * HID + off + t] = hn0;
        states[((size_t)srow * 64 + j1) * HID + off + t] = hn1;
    }
}

// ---------------------------------------------------------------------------
// ench (scrambled enc_hidden reshape) + G = ench @ W2^T + b2
// ---------------------------------------------------------------------------
__global__ __launch_bounds__(256) void k_ench(const float* __restrict__ states,
                                              const float* __restrict__ W2,
                                              const float* __restrict__ b2,
                                              float* __restrict__ ench,
                                              float* __restrict__ G) {
    __shared__ float es[512];
    int b = blockIdx.x, t = threadIdx.x;
    int p0 = 2 * b, p1 = 2 * b + 1;
    float v0 = (p0 < 64) ? states[((size_t)(SS - 1) * 64 + p0) * HID + t]
                         : states[((size_t)(p0 - 64)) * HID + 256 + t];
    float v1 = (p1 < 64) ? states[((size_t)(SS - 1) * 64 + p1) * HID + t]
                         : states[((size_t)(p1 - 64)) * HID + 256 + t];
    es[t] = v0; es[256 + t] = v1;
    ench[b * 512 + t] = v0; ench[b * 512 + 256 + t] = v1;
    __syncthreads();
    float a0 = 0, a1 = 0;
    for (int k = 0; k < 512; k += 4) {
        float4 e = *(const float4*)&es[k];
        float4 w0 = *(const float4*)(W2 + (size_t)t * 512 + k);
        float4 w1 = *(const float4*)(W2 + (size_t)(256 + t) * 512 + k);
        a0 += e.x * w0.x + e.y * w0.y + e.z * w0.z + e.w * w0.w;
        a1 += e.x * w1.x + e.y * w1.y + e.z * w1.z + e.w * w1.w;
    }
    G[b * 512 + t] = a0 + b2[t];
    G[b * 512 + 256 + t] = a1 + b2[256 + t];
}

// ---------------------------------------------------------------------------
// gate GEMM: states2 = states * sigmoid(states @ W1^T + b1 + G[b])
// ---------------------------------------------------------------------------
__global__ __launch_bounds__(256) void k_gate(const float* __restrict__ A,
                                              const float* __restrict__ W1,
                                              const float* __restrict__ b1,
                                              const float* __restrict__ G,
                                              float* __restrict__ out) {
    __shared__ float As[32][68];
    __shared__ float Ws[32][68];
    int tid = threadIdx.x, bx = blockIdx.x, by = blockIdx.y;
    int tx = tid & 15, ty = tid >> 4;
    float acc[4][4] = {};
    for (int k0 = 0; k0 < 512; k0 += 32) {
#pragma unroll
        for (int l = 0; l < 2; ++l) {
            int f = tid + l * 256;
            int r = f >> 3, c4 = f & 7;
            float4 v = *(const float4*)(A + ((size_t)by * 64 + r) * 512 + k0 + c4 * 4);
            As[c4 * 4 + 0][r] = v.x; As[c4 * 4 + 1][r] = v.y;
            As[c4 * 4 + 2][r] = v.z; As[c4 * 4 + 3][r] = v.w;
            float4 w = *(const float4*)(W1 + (size_t)(bx * 64 + r) * 512 + k0 + c4 * 4);
            Ws[c4 * 4 + 0][r] = w.x; Ws[c4 * 4 + 1][r] = w.y;
            Ws[c4 * 4 + 2][r] = w.z; Ws[c4 * 4 + 3][r] = w.w;
        }
        __syncthreads();
#pragma unroll
        for (int kk = 0; kk < 32; ++kk) {
            float4 a = *(const float4*)&As[kk][ty * 4];
            float4 w = *(const float4*)&Ws[kk][tx * 4];
            acc[0][0] += a.x * w.x; acc[0][1] += a.x * w.y; acc[0][2] += a.x * w.z; acc[0][3] += a.x * w.w;
            acc[1][0] += a.y * w.x; acc[1][1] += a.y * w.y; acc[1][2] += a.y * w.z; acc[1][3] += a.y * w.w;
            acc[2][0] += a.z * w.x; acc[2][1] += a.z * w.y; acc[2][2] += a.z * w.z; acc[2][3] += a.z * w.w;
            acc[3][0] += a.w * w.x; acc[3][1] += a.w * w.y; acc[3][2] += a.w * w.z; acc[3][3] += a.w * w.w;
        }
        __syncthreads();
    }
#pragma unroll
    for (int i = 0; i < 4; ++i)
#pragma unroll
        for (int j = 0; j < 4; ++j) {
            int m = by * 64 + ty * 4 + i, n = bx * 64 + tx * 4 + j;
            int b = ty * 4 + i;  // m % 64
            float x = acc[i][j] + b1[n] + G[(size_t)b * 512 + n];
            float g = 1.f / (1.f + expf(-x));
            out[(size_t)m * 512 + n] = A[(size_t)m * 512 + n] * g;
        }
}

// ---------------------------------------------------------------------------
// attn1[m] = dot(states2[m], Wa1) + ba1   (one wave per row)
// ---------------------------------------------------------------------------
__global__ __launch_bounds__(256) void k_attn1(const float* __restrict__ s2,
                                               const float* __restrict__ Wa1,
                                               const float* __restrict__ ba1,
                                               float* __restrict__ attn1) {
    int wid = threadIdx.x >> 6, lane = threadIdx.x & 63;
    int m = blockIdx.x * 4 + wid;
    const float* row = s2 + (size_t)m * 512;
    float acc = 0;
    for (int i = lane; i < 512; i += 64) acc += row[i] * Wa1[i];
    for (int off = 32; off > 0; off >>= 1) acc += __shfl_down(acc, off, 64);
    if (lane == 0) attn1[m] = acc + ba1[0];
}

// ---------------------------------------------------------------------------
// decoder init: h = ench, loss = 0
// ---------------------------------------------------------------------------
__global__ void k_dec_init(const float* __restrict__ ench, float* __restrict__ h,
                           float* __restrict__ loss) {
    int gid = blockIdx.x * 256 + threadIdx.x;
    if (gid < 64 * 512) h[gid] = ench[gid];
    if (gid == 0) loss[0] = 0.f;
}

// ---------------------------------------------------------------------------
// attention scores + faithful scrambled softmax.  block = one softmax row r.
// scores_flat[i] = attn1[i] + a2[i%64]; softmax over i in [r*200,(r+1)*200)
// ---------------------------------------------------------------------------
__global__ __launch_bounds__(256) void k_attn_soft(const float* __restrict__ h,
                                                   const float* __restrict__ Wa2,
                                                   const float* __restrict__ ba2,
                                                   const float* __restrict__ attn1,
                                                   float* __restrict__ aw) {
    __shared__ float a2s[64];
    __shared__ float red[256];
    int r = blockIdx.x, t = threadIdx.x;
    int b = t >> 2, q = t & 3;
    float part = 0;
    for (int i = 0; i < 128; ++i) {
        int k = q + 4 * i;
        part += h[(size_t)b * 512 + k] * Wa2[k];
    }
    red[t] = part;
    __syncthreads();
    if (t < 64) a2s[t] = red[t * 4] + red[t * 4 + 1] + red[t * 4 + 2] + red[t * 4 + 3] + ba2[0];
    __syncthreads();
    int iflat = r * 200 + t;
    float val = (t < 200) ? attn1[iflat] + a2s[iflat & 63] : -3.4e38f;
    red[t] = val;
    __syncthreads();
    for (int s = 128; s > 0; s >>= 1) {
        if (t < s) red[t] = fmaxf(red[t], red[t + s]);
        __syncthreads();
    }
    float mx = red[0];
    __syncthreads();
    float e = (t < 200) ? expf(val - mx) : 0.f;
    red[t] = e;
    __syncthreads();
    for (int s = 128; s > 0; s >>= 1) {
        if (t < s) red[t] += red[t + s];
        __syncthreads();
    }
    float sum = red[0];
    if (t < 200) aw[iflat] = e / sum;
}

// ---------------------------------------------------------------------------
// context + xcat build: xcat[b] = [emb[w_in[b]], sum_s aw[s*64+b]*states2[s,b]]
// ---------------------------------------------------------------------------
__global__ __launch_bounds__(256) void k_ctx(const float* __restrict__ aw,
                                             const float* __restrict__ s2,
                                             const float* __restrict__ emb,
                                             const int* __restrict__ trg,
                                             int step, float* __restrict__ xcat) {
    int b = blockIdx.x, t = threadIdx.x;
    int wi = trg[b * TT + step];
    xcat[b * 768 + t] = emb[(size_t)wi * EE + t];
    float a0 = 0, a1 = 0;
    for (int s = 0; s < SS; ++s) {
        float a = aw[s * 64 + b];
        const float* row = s2 + ((size_t)s * 64 + b) * 512;
        a0 += a * row[t];
        a1 += a * row[256 + t];
    }
    xcat[b * 768 + 256 + t] = a0;
    xcat[b * 768 + 512 + t] = a1;
}

// ---------------------------------------------------------------------------
// decoder GRU GEMMs: blocks 0..47: gi_d = xcat@Wihd^T+b (K=768);
//                    blocks 48..95: gh_d = h@Whhd^T+b (K=512). BN=32.
// ---------------------------------------------------------------------------
__global__ __launch_bounds__(256) void k_grud(const float* __restrict__ xcat,
                                              const float* __restrict__ h,
                                              const float* __restrict__ wih,
                                              const float* __restrict__ whh,
                                              const float* __restrict__ bih,
                                              const float* __restrict__ bhh,
                                              float* __restrict__ gid_,
                                              float* __restrict__ ghd) {
    __shared__ float As[32][68];
    __shared__ float Ws[32][36];
    int z = blockIdx.x;
    bool second = z >= 48;
    const float* A = second ? h : xcat;
    const float* W = second ? whh : wih;
    const float* bias = second ? bhh : bih;
    float* out = second ? ghd : gid_;
    int K = second ? 512 : 768;
    int n0 = (second ? z - 48 : z) * 32;
    int tid = threadIdx.x;
    int tx = tid & 15, ty = tid >> 4;
    float acc[4][2] = {};
    for (int k0 = 0; k0 < K; k0 += 32) {
#pragma unroll
        for (int l = 0; l < 2; ++l) {
            int f = tid + l * 256;
            int r = f >> 3, c4 = f & 7;
            float4 v = *(const float4*)(A + (size_t)r * K + k0 + c4 * 4);
            As[c4 * 4 + 0][r] = v.x; As[c4 * 4 + 1][r] = v.y;
            As[c4 * 4 + 2][r] = v.z; As[c4 * 4 + 3][r] = v.w;
        }
        {
            int r = tid >> 3, c4 = tid & 7;
            float4 w = *(const float4*)(W + (size_t)(n0 + r) * K + k0 + c4 * 4);
            Ws[c4 * 4 + 0][r] = w.x; Ws[c4 * 4 + 1][r] = w.y;
            Ws[c4 * 4 + 2][r] = w.z; Ws[c4 * 4 + 3][r] = w.w;
        }
        __syncthreads();
#pragma unroll
        for (int kk = 0; kk < 32; ++kk) {
            float4 a = *(const float4*)&As[kk][ty * 4];
            float2 w = *(const float2*)&Ws[kk][tx * 2];
            acc[0][0] += a.x * w.x; acc[0][1] += a.x * w.y;
            acc[1][0] += a.y * w.x; acc[1][1] += a.y * w.y;
            acc[2][0] += a.z * w.x; acc[2][1] += a.z * w.y;
            acc[3][0] += a.w * w.x; acc[3][1] += a.w * w.y;
        }
        __syncthreads();
    }
#pragma unroll
    for (int i = 0; i < 4; ++i)
#pragma unroll
        for (int j = 0; j < 2; ++j) {
            int m = ty * 4 + i, n = n0 + tx * 2 + j;
            out[(size_t)m * 1536 + n] = acc[i][j] + bias[n];
        }
}

// ---------------------------------------------------------------------------
// decoder GRU elementwise update (in place on h)
// ---------------------------------------------------------------------------
__global__ void k_hnew(const float* __restrict__ gi, const float* __restrict__ gh,
                       float* __restrict__ h) {
    int gid = blockIdx.x * 256 + threadIdx.x;  // 32768
    int b = gid >> 9, k = gid & 511;
    float gir = gi[b * 1536 + k], giz = gi[b * 1536 + 512 + k], gin = gi[b * 1536 + 1024 + k];
    float ghr = gh[b * 1536 + k], ghz = gh[b * 1536 + 512 + k], ghn = gh[b * 1536 + 1024 + k];
    float r = 1.f / (1.f + expf(-(gir + ghr)));
    float z = 1.f / (1.f + expf(-(giz + ghz)));
    float n = tanhf(gin + r * ghn);
    h[gid] = (1.f - z) * n + z * h[gid];
}

// ---------------------------------------------------------------------------
// vocab GEMM: logits[64][32000] = h @ Wv^T + bv
// ---------------------------------------------------------------------------
__global__ __launch_bounds__(256) void k_vocab(const float* __restrict__ A,
                                               const float* __restrict__ Wv,
                                               const float* __restrict__ bv,
                                               float* __restrict__ logits) {
    __shared__ float As[32][68];
    __shared__ float Ws[32][68];
    int tid = threadIdx.x, bx = blockIdx.x;
    int tx = tid & 15, ty = tid >> 4;
    float acc[4][4] = {};
    for (int k0 = 0; k0 < 512; k0 += 32) {
#pragma unroll
        for (int l = 0; l < 2; ++l) {
            int f = tid + l * 256;
            int r = f >> 3, c4 = f & 7;
            float4 v = *(const float4*)(A + (size_t)r * 512 + k0 + c4 * 4);
            As[c4 * 4 + 0][r] = v.x; As[c4 * 4 + 1][r] = v.y;
            As[c4 * 4 + 2][r] = v.z; As[c4 * 4 + 3][r] = v.w;
            float4 w = *(const float4*)(Wv + (size_t)(bx * 64 + r) * 512 + k0 + c4 * 4);
            Ws[c4 * 4 + 0][r] = w.x; Ws[c4 * 4 + 1][r] = w.y;
            Ws[c4 * 4 + 2][r] = w.z; Ws[c4 * 4 + 3][r] = w.w;
        }
        __syncthreads();
#pragma unroll
        for (int kk = 0; kk < 32; ++kk) {
            float4 a = *(const float4*)&As[kk][ty * 4];
            float4 w = *(const float4*)&Ws[kk][tx * 4];
            acc[0][0] += a.x * w.x; acc[0][1] += a.x * w.y; acc[0][2] += a.x * w.z; acc[0][3] += a.x * w.w;
            acc[1][0] += a.y * w.x; acc[1][1] += a.y * w.y; acc[1][2] += a.y * w.z; acc[1][3] += a.y * w.w;
            acc[2][0] += a.z * w.x; acc[2][1] += a.z * w.y; acc[2][2] += a.z * w.z; acc[2][3] += a.z * w.w;
            acc[3][0] += a.w * w.x; acc[3][1] += a.w * w.y; acc[3][2] += a.w * w.z; acc[3][3] += a.w * w.w;
        }
        __syncthreads();
    }
#pragma unroll
    for (int i = 0; i < 4; ++i)
#pragma unroll
        for (int j = 0; j < 4; ++j) {
            int m = ty * 4 + i, n = bx * 64 + tx * 4 + j;
            logits[(size_t)m * VV + n] = acc[i][j] + bv[n];
        }
}

// ---------------------------------------------------------------------------
// per-row log-softmax NLL, accumulated into loss via atomicAdd
// ---------------------------------------------------------------------------
__global__ __launch_bounds__(256) void k_loss(const float* __restrict__ logits,
                                              const int* __restrict__ trg, int step,
                                              float* __restrict__ loss) {
    __shared__ float red[256];
    int b = blockIdx.x, t = threadIdx.x;
    const float* row = logits + (size_t)b * VV;
    float mx = -3.4e38f;
    for (int i = t; i < VV; i += 256) mx = fmaxf(mx, row[i]);
    red[t] = mx;
    __syncthreads();
    for (int s = 128; s > 0; s >>= 1) {
        if (t < s) red[t] = fmaxf(red[t], red[t + s]);
        __syncthreads();
    }
    mx = red[0];
    __syncthreads();
    float sum = 0;
    for (int i = t; i < VV; i += 256) sum += expf(row[i] - mx);
    red[t] = sum;
    __syncthreads();
    for (int s = 128; s > 0; s >>= 1) {
        if (t < s) red[t] += red[t + s];
        __syncthreads();
    }
    if (t == 0) {
        int tgt = trg[b * TT + step + 1];
        atomicAdd(loss, mx + logf(red[0]) - row[tgt]);
    }
}

__global__ void k_final(const float* __restrict__ loss, float* __restrict__ out) {
    out[0] = loss[0] * (1.f / (64.f * 25.f));
}

// ---------------------------------------------------------------------------
extern "C" void kernel_launch(void* const* d_in, const int* in_sizes, int n_in,
                              void* d_out, int out_size, void* d_ws, size_t ws_size,
                              hipStream_t stream) {
    const int* src = (const int*)d_in[0];
    const int* trg = (const int*)d_in[1];
    const float* emb = (const float*)d_in[2];
    const float* w_ih_f = (const float*)d_in[3];
    const float* w_hh_f = (const float*)d_in[4];
    const float* b_ih_f = (const float*)d_in[5];
    const float* b_hh_f = (const float*)d_in[6];
    const float* w_ih_b = (const float*)d_in[7];
    const float* w_hh_b = (const float*)d_in[8];
    const float* b_ih_b = (const float*)d_in[9];
    const float* b_hh_b = (const float*)d_in[10];
    const float* W1 = (const float*)d_in[11];
    const float* b1 = (const float*)d_in[12];
    const float* W2 = (const float*)d_in[13];
    const float* b2 = (const float*)d_in[14];
    const float* w_ih_d = (const float*)d_in[15];
    const float* w_hh_d = (const float*)d_in[16];
    const float* b_ih_d = (const float*)d_in[17];
    const float* b_hh_d = (const float*)d_in[18];
    const float* Wv = (const float*)d_in[19];
    const float* bv = (const float*)d_in[20];
    const float* Wa1 = (const float*)d_in[21];
    const float* ba1 = (const float*)d_in[22];
    const float* Wa2 = (const float*)d_in[23];
    const float* ba2 = (const float*)d_in[24];

    float* ws = (float*)d_ws;
    float* giF = ws;                          // 12800*768
    float* giB = giF + 12800 * 768;           // 12800*768
    float* states = giB + 12800 * 768;        // 12800*512
    float* states2 = states + 12800 * 512;    // 12800*512
    float* wTf = states2 + 12800 * 512;       // 196608
    float* wTb = wTf + 196608;                // 196608
    float* ench = wTb + 196608;               // 32768
    float* G = ench + 32768;                  // 32768
    float* attn1 = G + 32768;                 // 12800
    float* aw = attn1 + 12800;                // 12800
    float* xcat = aw + 12800;                 // 49152
    float* hdec = xcat + 49152;               // 32768
    float* gid_ = hdec + 32768;               // 98304
    float* ghd = gid_ + 98304;                // 98304
    float* logits = ghd + 98304;              // 64*32000
    float* lossp = logits + (size_t)64 * VV;  // 1

    k_whh_pack<<<(2 * 768 * 256 + 255) / 256, 256, 0, stream>>>(w_hh_f, w_hh_b, wTf, wTb);
    k_gemm_gi<<<dim3(12, 200), 256, 0, stream>>>(src, emb, w_ih_f, b_ih_f, giF);
    k_gemm_gi<<<dim3(12, 200), 256, 0, stream>>>(src, emb, w_ih_b, b_ih_b, giB);
    k_scan<<<64, 256, 0, stream>>>(giF, giB, wTf, wTb, b_hh_f, b_hh_b, states);
    k_ench<<<64, 256, 0, stream>>>(states, W2, b2, ench, G);
    k_gate<<<dim3(8, 200), 256, 0, stream>>>(states, W1, b1, G, states2);
    k_attn1<<<3200, 256, 0, stream>>>(states2, Wa1, ba1, attn1);
    k_dec_init<<<128, 256, 0, stream>>>(ench, hdec, lossp);

    for (int t = 0; t < TT - 1; ++t) {
        k_attn_soft<<<64, 256, 0, stream>>>(hdec, Wa2, ba2, attn1, aw);
        k_ctx<<<64, 256, 0, stream>>>(aw, states2, emb, trg, t, xcat);
        k_grud<<<96, 256, 0, stream>>>(xcat, hdec, w_ih_d, w_hh_d, b_ih_d, b_hh_d, gid_, ghd);
        k_hnew<<<128, 256, 0, stream>>>(gid_, ghd, hdec);
        k_vocab<<<500, 256, 0, stream>>>(hdec, Wv, bv, logits);
        k_loss<<<64, 256, 0, stream>>>(logits, trg, t, lossp);
    }
    k_final<<<1, 1, 0, stream>>>(lossp, (float*)d_out);
}